// Round 5
// baseline (190.751 us; speedup 1.0000x reference)
//
#include <hip/hip_runtime.h>

// GraphAttentionLayer, B=8, N=1024, F_IN=64, HEADS=8, D=64.
// exp(leaky_relu(s_i + t_j)) factorizes across the LeakyReLU branch:
//   [s_i+t_j>0] e^{s_i} e^{t_j} + [s_i+t_j<=0] e^{0.01 s_i} e^{0.01 t_j}
// so softmax denominators (over i) and the weighted sum over j reduce to
// prefix sums over sorted s / sorted t.  O(N^2 D) -> O(N log N + N D).
//
// R5: R4 structure + fix: re-zero cntL[1024] before the scatter phase
// (rank-1024 queries were scattering OOB into startG -> device fault).
//   kS  (128 blocks x 1024): s-sort and t-sort in SEPARATE blocks (parity)
//   kM  ( 64 blocks x 1024): scans, Z/u/v, ranks, counting-sort, chunk sums
//   kW  (1024 blocks x  64): independent chunk prefix walks + query emission
// Pipeline: k_wh -> kS -> kM -> kW -> k_out.

#define B_  8
#define N_  1024
#define H_  8
#define D_  64
#define BH_ 64
#define NCH 16          // chunks per (b,h)
#define CLN 64          // ranks per chunk

// ---------------- Kernel A: Wh = h@W (row-blocked), s/t = Wh . a ----------
__global__ __launch_bounds__(256) void k_wh(
    const float* __restrict__ h, const float* __restrict__ W,
    const float* __restrict__ a,
    float* __restrict__ Wh, float* __restrict__ sArr, float* __restrict__ tArr) {
  __shared__ float hL[16 * 64];
  __shared__ float whL[16 * 512];
  __shared__ float aL[128];
  const int tid = threadIdx.x;
  const int row0 = blockIdx.x * 16;
  const int b = row0 >> 10;
  for (int i = tid; i < 16 * 64; i += 256) hL[i] = h[row0 * 64 + i];
  if (tid < 128) aL[tid] = a[tid];
  __syncthreads();

  float acc0[16], acc1[16];
#pragma unroll
  for (int r = 0; r < 16; ++r) { acc0[r] = 0.f; acc1[r] = 0.f; }
  for (int k = 0; k < 64; ++k) {
    const float w0 = W[k * 512 + tid];
    const float w1 = W[k * 512 + tid + 256];
#pragma unroll
    for (int r = 0; r < 16; ++r) {
      const float hv = hL[r * 64 + k];
      acc0[r] += hv * w0;
      acc1[r] += hv * w1;
    }
  }
  const int hh0 = tid >> 6, d0 = tid & 63;
  const int hh1 = (tid + 256) >> 6;
#pragma unroll
  for (int r = 0; r < 16; ++r) {
    const int n = (row0 + r) & (N_ - 1);
    whL[r * 512 + tid] = acc0[r];
    whL[r * 512 + tid + 256] = acc1[r];
    Wh[((b * H_ + hh0) * N_ + n) * D_ + d0] = acc0[r];
    Wh[((b * H_ + hh1) * N_ + n) * D_ + d0] = acc1[r];
  }
  __syncthreads();
  if (tid < 128) {
    const int r = tid >> 3, hh = tid & 7;
    const int n = (row0 + r) & (N_ - 1);
    float accS = 0.f, accT = 0.f;
    for (int jj = 0; jj < 64; ++jj) {
      const int d = (jj + tid) & 63;
      const float wv = whL[r * 512 + hh * 64 + d];
      accS += wv * aL[d];
      accT += wv * aL[64 + d];
    }
    sArr[(b * H_ + hh) * N_ + n] = accS;
    tArr[(b * H_ + hh) * N_ + n] = accT;
  }
}

// ---- Kernel S: one 1024-element bitonic sort per block; parity: s or t ----
__global__ __launch_bounds__(1024) void k_sort1(
    const float* __restrict__ sArr, const float* __restrict__ tArr,
    float* __restrict__ ssv, float* __restrict__ tsv, int* __restrict__ tsi) {
  __shared__ float vL[1024];
  __shared__ int   iL[1024];
  const int tid = threadIdx.x;
  const int bh = blockIdx.x >> 1;
  const bool isT = (blockIdx.x & 1) != 0;
  if (isT) {
    float v = tArr[bh * N_ + tid];
    int   idx = tid;
    for (int size = 2; size <= 1024; size <<= 1) {
      for (int stride = size >> 1; stride > 0; stride >>= 1) {
        const bool up = ((tid & size) == 0);
        const bool lower = ((tid & stride) == 0);
        float pv; int pi;
        if (stride >= 64) {
          __syncthreads();
          vL[tid] = v; iL[tid] = idx;
          __syncthreads();
          pv = vL[tid ^ stride]; pi = iL[tid ^ stride];
        } else {
          pv = __shfl_xor(v, stride);
          pi = __shfl_xor(idx, stride);
        }
        const bool sameDir = (up == lower);
        const bool pLess = (pv < v) || (pv == v && pi < idx);
        if (pLess == sameDir) { v = pv; idx = pi; }
      }
    }
    tsv[bh * N_ + tid] = v; tsi[bh * N_ + tid] = idx;
  } else {
    float v = sArr[bh * N_ + tid];
    for (int size = 2; size <= 1024; size <<= 1) {
      for (int stride = size >> 1; stride > 0; stride >>= 1) {
        const bool up = ((tid & size) == 0);
        const bool lower = ((tid & stride) == 0);
        float pv;
        if (stride >= 64) {
          __syncthreads();
          vL[tid] = v;
          __syncthreads();
          pv = vL[tid ^ stride];
        } else {
          pv = __shfl_xor(v, stride);
        }
        const bool sameDir = (up == lower);
        if ((pv < v) == sameDir) v = pv;
      }
    }
    ssv[bh * N_ + tid] = v;
  }
}

// ---- Kernel M: scans, Z/u/v, query ranks + counting-sort, chunk sums ----
__global__ __launch_bounds__(1024) void k_mid2(
    const float* __restrict__ sArr,
    const float* __restrict__ ssv, const float* __restrict__ tsv,
    const int* __restrict__ tsi, const float* __restrict__ Wh,
    float* __restrict__ uArr, float* __restrict__ vArr,
    float* __restrict__ esG, float* __restrict__ es001G,
    int* __restrict__ startG, int* __restrict__ qListG,
    float* __restrict__ cOff1, float* __restrict__ cOff2,
    float* __restrict__ T1G) {
  __shared__ float sL[1024], tvL[1024];
  __shared__ int   tiL[1024];
  __shared__ float cum1L[1024], cum001L[1024];
  __shared__ float uL[1024], vL[1024];
  __shared__ int   cntL[1025], startL[1025];
  __shared__ float cs1[NCH * 64], cs2[NCH * 64];
  __shared__ float wf1[16], wf2[16];
  __shared__ int   wi1[16];
  const int tid = threadIdx.x, lane = tid & 63, wv = tid >> 6;
  const int bh = blockIdx.x;
  const int base = bh * N_;

  const float sv = ssv[base + tid];       // sorted s value at rank tid
  const float tj = tsv[base + tid];       // sorted t value at rank tid
  sL[tid] = sv; tvL[tid] = tj; tiL[tid] = tsi[base + tid];
  const float orig_s = sArr[base + tid];
  cntL[tid] = 0;
  if (tid == 0) cntL[1024] = 0;

  // inclusive scans of exp(sorted s), exp(0.01 * sorted s)
  {
    float a1 = __expf(sv), a2 = __expf(0.01f * sv);
#pragma unroll
    for (int off = 1; off < 64; off <<= 1) {
      const float x1 = __shfl_up(a1, off);
      const float x2 = __shfl_up(a2, off);
      if (lane >= off) { a1 += x1; a2 += x2; }
    }
    if (lane == 63) { wf1[wv] = a1; wf2[wv] = a2; }
    __syncthreads();
    float o1 = 0.f, o2 = 0.f;
    for (int ww = 0; ww < 16; ++ww) {
      if (ww < wv) { o1 += wf1[ww]; o2 += wf2[ww]; }
    }
    cum1L[tid] = a1 + o1; cum001L[tid] = a2 + o2;
  }
  __syncthreads();
  const float totalHi = cum1L[1023];

  // per sorted-t rank: Z, u = e^t/Z, v = e^{0.01t}/Z
  {
    const float th = -tj;
    int lo = 0, hi = 1024;   // count of sorted-s <= th
    while (lo < hi) { const int mid = (lo + hi) >> 1; if (sL[mid] <= th) lo = mid + 1; else hi = mid; }
    const float S_lo = (lo > 0) ? cum001L[lo - 1] : 0.f;
    const float S_hi = totalHi - ((lo > 0) ? cum1L[lo - 1] : 0.f);
    const float et = __expf(tj), et001 = __expf(0.01f * tj);
    const float Z = et * S_hi + et001 * S_lo;
    const float u = et / Z, v = et001 / Z;
    uL[tid] = u; vL[tid] = v;
    uArr[base + tid] = u; vArr[base + tid] = v;
  }

  // query rank for row i=tid: count of t_j <= -s_i ; histogram
  int rk;
  {
    const float th = -orig_s;
    int lo = 0, hi = 1024;
    while (lo < hi) { const int mid = (lo + hi) >> 1; if (tvL[mid] <= th) lo = mid + 1; else hi = mid; }
    rk = lo;
    atomicAdd(&cntL[rk], 1);
    esG[base + tid] = __expf(orig_s);
    es001G[base + tid] = __expf(0.01f * orig_s);
  }
  __syncthreads();

  // exclusive scan of cntL -> startL, write startG
  {
    const int cown = cntL[tid];
    int a = cown;
#pragma unroll
    for (int off = 1; off < 64; off <<= 1) {
      const int x = __shfl_up(a, off);
      if (lane >= off) a += x;
    }
    if (lane == 63) wi1[wv] = a;
    __syncthreads();
    int o = 0;
    for (int ww = 0; ww < 16; ++ww) {
      if (ww < wv) o += wi1[ww];
    }
    const int incl = a + o;
    startL[tid] = incl - cown;
    startG[bh * 1025 + tid] = incl - cown;
    if (tid == 1023) { startL[1024] = incl; startG[bh * 1025 + 1024] = incl; }
  }
  __syncthreads();
  cntL[tid] = 0;
  if (tid == 0) cntL[1024] = 0;   // FIX: rank-1024 bin must be re-zeroed too
  __syncthreads();
  // scatter queries grouped by rank
  {
    const int pos = startL[rk] + atomicAdd(&cntL[rk], 1);
    qListG[base + pos] = tid;
  }

  // chunk sums of u*Wh, v*Wh over sorted-t ranks (chunk = wave)
  {
    float s1 = 0.f, s2 = 0.f;
    for (int k2 = 0; k2 < CLN; ++k2) {
      const int k = wv * CLN + k2;
      const int j = tiL[k];
      const float w = Wh[(base + j) * D_ + lane];
      s1 += uL[k] * w;
      s2 += vL[k] * w;
    }
    cs1[wv * 64 + lane] = s1; cs2[wv * 64 + lane] = s2;
  }
  __syncthreads();

  // exclusive chunk offsets + total
  {
    float o1 = 0.f, o2 = 0.f, T1 = 0.f;
    for (int m = 0; m < NCH; ++m) {
      const float v1 = cs1[m * 64 + lane];
      if (m < wv) { o1 += v1; o2 += cs2[m * 64 + lane]; }
      T1 += v1;
    }
    cOff1[(bh * NCH + wv) * 64 + lane] = o1;
    cOff2[(bh * NCH + wv) * 64 + lane] = o2;
    if (wv == NCH - 1) T1G[bh * 64 + lane] = T1;
  }
}

// ---- Kernel W: block = (bh, chunk): independent prefix walk + emission ----
__global__ __launch_bounds__(64) void k_walk(
    const float* __restrict__ Wh, const int* __restrict__ tsi,
    const float* __restrict__ uArr, const float* __restrict__ vArr,
    const int* __restrict__ startG, const int* __restrict__ qListG,
    const float* __restrict__ esG, const float* __restrict__ es001G,
    const float* __restrict__ cOff1, const float* __restrict__ cOff2,
    const float* __restrict__ T1G, float* __restrict__ hp) {
  const int blk = blockIdx.x;           // bh*NCH + c
  const int bh = blk >> 4, c = blk & (NCH - 1);
  const int lane = threadIdx.x;
  const int b = bh >> 3, hh = bh & 7;
  const int base = bh * N_;

  float r1 = cOff1[blk * 64 + lane];
  float r2 = cOff2[blk * 64 + lane];
  const float T1 = T1G[bh * 64 + lane];
  // per-lane slice preloads; broadcast via shfl in the walk
  const int   tiR = tsi[base + c * CLN + lane];
  const float uR  = uArr[base + c * CLN + lane];
  const float vR  = vArr[base + c * CLN + lane];
  const int   stR = startG[bh * 1025 + c * CLN + lane];
  const int   stEnd = startG[bh * 1025 + c * CLN + 64];

#pragma unroll 4
  for (int k2 = 0; k2 < CLN; ++k2) {
    const int qs = __shfl(stR, k2);
    const int qe = (k2 < 63) ? __shfl(stR, k2 + 1) : stEnd;
    for (int q = qs; q < qe; ++q) {
      const int i = qListG[base + q];
      const float es = esG[base + i], es001 = es001G[base + i];
      hp[((b * N_ + i) << 9) + (hh << 6) + lane] = es * (T1 - r1) + es001 * r2;
    }
    const int j = __shfl(tiR, k2);
    const float w = Wh[(base + j) * D_ + lane];
    r1 += __shfl(uR, k2) * w;
    r2 += __shfl(vR, k2) * w;
  }
  if (c == NCH - 1) {
    // queries with rank == 1024 (all t_j <= -s_i)
    for (int q = stEnd; q < N_; ++q) {
      const int i = qListG[base + q];
      const float es = esG[base + i], es001 = es001G[base + i];
      hp[((b * N_ + i) << 9) + (hh << 6) + lane] = es * (T1 - r1) + es001 * r2;
    }
  }
}

// ---- Kernel C: out[row] = hp[row] @ outW + outb (coalesced hp reads) -----
__global__ __launch_bounds__(512) void k_out(
    const float* __restrict__ hp,
    const float* __restrict__ outW, const float* __restrict__ outb,
    float* __restrict__ out) {
  __shared__ float hpL[16 * 512];
  __shared__ float part[8 * 8 * 64];
  const int tid = threadIdx.x;
  const int row0 = blockIdx.x * 16;
  for (int i = tid; i < 16 * 512; i += 512) hpL[i] = hp[row0 * 512 + i];
  __syncthreads();

  const int cc = tid & 63, p = tid >> 6;
  float acc[16];
#pragma unroll
  for (int r = 0; r < 16; ++r) acc[r] = 0.f;
  for (int k = p * 64; k < p * 64 + 64; ++k) {
    const float wvv = outW[k * 64 + cc];
#pragma unroll
    for (int r = 0; r < 16; ++r) acc[r] += hpL[r * 512 + k] * wvv;
  }
  for (int half = 0; half < 2; ++half) {
#pragma unroll
    for (int r = 0; r < 8; ++r) part[(p * 8 + r) * 64 + cc] = acc[half * 8 + r];
    __syncthreads();
    {
      const int r = tid >> 6, c2 = tid & 63;
      float ssum = 0.f;
#pragma unroll
      for (int p2 = 0; p2 < 8; ++p2) ssum += part[(p2 * 8 + r) * 64 + c2];
      out[(row0 + half * 8 + r) * 64 + c2] = outb[c2] + ssum;
    }
    __syncthreads();
  }
}

extern "C" void kernel_launch(void* const* d_in, const int* in_sizes, int n_in,
                              void* d_out, int out_size, void* d_ws, size_t ws_size,
                              hipStream_t stream) {
  const float* h    = (const float*)d_in[0];
  // d_in[1] = adj: all-ones, unused by the module
  const float* W    = (const float*)d_in[2];
  const float* a    = (const float*)d_in[3];
  const float* outW = (const float*)d_in[4];
  const float* outb = (const float*)d_in[5];
  float* out = (float*)d_out;

  float* ws    = (float*)d_ws;
  float* Wh    = ws;                                  // 4,194,304 f (16 MB)
  float* hpG   = Wh + (size_t)BH_ * N_ * D_;          // 4,194,304 f (16 MB)
  float* sArr  = hpG + (size_t)B_ * N_ * 512;         // 65536 each below
  float* tArr  = sArr + BH_ * N_;
  float* ssv   = tArr + BH_ * N_;
  float* tsv   = ssv + BH_ * N_;
  int*   tsi   = (int*)(tsv + BH_ * N_);
  float* uArr  = (float*)(tsi + BH_ * N_);
  float* vArr  = uArr + BH_ * N_;
  float* esG   = vArr + BH_ * N_;
  float* es001G= esG + BH_ * N_;
  int*   qListG= (int*)(es001G + BH_ * N_);
  int*   startG= qListG + BH_ * N_;                   // 64*1025
  float* cOff1 = (float*)(startG + BH_ * 1025);       // 64*16*64
  float* cOff2 = cOff1 + BH_ * NCH * 64;
  float* T1G   = cOff2 + BH_ * NCH * 64;              // 64*64

  hipLaunchKernelGGL(k_wh,    dim3((B_ * N_) / 16), dim3(256), 0, stream,
                     h, W, a, Wh, sArr, tArr);
  hipLaunchKernelGGL(k_sort1, dim3(BH_ * 2), dim3(1024), 0, stream,
                     sArr, tArr, ssv, tsv, tsi);
  hipLaunchKernelGGL(k_mid2,  dim3(BH_), dim3(1024), 0, stream,
                     sArr, ssv, tsv, tsi, Wh,
                     uArr, vArr, esG, es001G, startG, qListG, cOff1, cOff2, T1G);
  hipLaunchKernelGGL(k_walk,  dim3(BH_ * NCH), dim3(64), 0, stream,
                     Wh, tsi, uArr, vArr, startG, qListG, esG, es001G,
                     cOff1, cOff2, T1G, hpG);
  hipLaunchKernelGGL(k_out,   dim3((B_ * N_) / 16), dim3(512), 0, stream,
                     hpG, outW, outb, out);
}

// Round 6
// 159.209 us; speedup vs baseline: 1.1981x; 1.1981x over previous
//
#include <hip/hip_runtime.h>

// GraphAttentionLayer, B=8, N=1024, F_IN=64, HEADS=8, D=64.
// exp(leaky_relu(s_i + t_j)) factorizes across the LeakyReLU branch:
//   [s_i+t_j>0] e^{s_i} e^{t_j} + [s_i+t_j<=0] e^{0.01 s_i} e^{0.01 t_j}
// so softmax denominators (over i) and the weighted sum over j reduce to
// prefix sums over sorted s / sorted t.  O(N^2 D) -> O(N log N + N D).
//
// R6: R5's k_walk (49us: 2-level dependent GLOBAL load chain per emission,
// 1 wave/block) fused back into the 16-wave k_mid kernel:
//  - emissions read a single LDS float4 qPack record (i, e^s, e^{0.01s})
//  - walk runs from VGPR-resident Wh chunk rows (loaded once in chunk-sum)
//  - kills k_walk dispatch + 16MB Wh re-read + all small-array round-trips
// Pipeline: k_wh -> k_sort1 -> k_mid3 -> k_out.  ws: 50 -> 33 MB.

#define B_  8
#define N_  1024
#define H_  8
#define D_  64
#define BH_ 64
#define NCH 16          // chunks per (b,h) == waves per block
#define CLN 64          // ranks per chunk

// ---------------- Kernel A: Wh = h@W (row-blocked), s/t = Wh . a ----------
__global__ __launch_bounds__(256) void k_wh(
    const float* __restrict__ h, const float* __restrict__ W,
    const float* __restrict__ a,
    float* __restrict__ Wh, float* __restrict__ sArr, float* __restrict__ tArr) {
  __shared__ float hL[16 * 64];
  __shared__ float whL[16 * 512];
  __shared__ float aL[128];
  const int tid = threadIdx.x;
  const int row0 = blockIdx.x * 16;
  const int b = row0 >> 10;
  for (int i = tid; i < 16 * 64; i += 256) hL[i] = h[row0 * 64 + i];
  if (tid < 128) aL[tid] = a[tid];
  __syncthreads();

  float acc0[16], acc1[16];
#pragma unroll
  for (int r = 0; r < 16; ++r) { acc0[r] = 0.f; acc1[r] = 0.f; }
  for (int k = 0; k < 64; ++k) {
    const float w0 = W[k * 512 + tid];
    const float w1 = W[k * 512 + tid + 256];
#pragma unroll
    for (int r = 0; r < 16; ++r) {
      const float hv = hL[r * 64 + k];
      acc0[r] += hv * w0;
      acc1[r] += hv * w1;
    }
  }
  const int hh0 = tid >> 6, d0 = tid & 63;
  const int hh1 = (tid + 256) >> 6;
#pragma unroll
  for (int r = 0; r < 16; ++r) {
    const int n = (row0 + r) & (N_ - 1);
    whL[r * 512 + tid] = acc0[r];
    whL[r * 512 + tid + 256] = acc1[r];
    Wh[((b * H_ + hh0) * N_ + n) * D_ + d0] = acc0[r];
    Wh[((b * H_ + hh1) * N_ + n) * D_ + d0] = acc1[r];
  }
  __syncthreads();
  if (tid < 128) {
    const int r = tid >> 3, hh = tid & 7;
    const int n = (row0 + r) & (N_ - 1);
    float accS = 0.f, accT = 0.f;
    for (int jj = 0; jj < 64; ++jj) {
      const int d = (jj + tid) & 63;
      const float wv = whL[r * 512 + hh * 64 + d];
      accS += wv * aL[d];
      accT += wv * aL[64 + d];
    }
    sArr[(b * H_ + hh) * N_ + n] = accS;
    tArr[(b * H_ + hh) * N_ + n] = accT;
  }
}

// ---- Kernel S: one 1024-element bitonic sort per block; parity: s or t ----
__global__ __launch_bounds__(1024) void k_sort1(
    const float* __restrict__ sArr, const float* __restrict__ tArr,
    float* __restrict__ ssv, float* __restrict__ tsv, int* __restrict__ tsi) {
  __shared__ float vL[1024];
  __shared__ int   iL[1024];
  const int tid = threadIdx.x;
  const int bh = blockIdx.x >> 1;
  const bool isT = (blockIdx.x & 1) != 0;
  if (isT) {
    float v = tArr[bh * N_ + tid];
    int   idx = tid;
    for (int size = 2; size <= 1024; size <<= 1) {
      for (int stride = size >> 1; stride > 0; stride >>= 1) {
        const bool up = ((tid & size) == 0);
        const bool lower = ((tid & stride) == 0);
        float pv; int pi;
        if (stride >= 64) {
          __syncthreads();
          vL[tid] = v; iL[tid] = idx;
          __syncthreads();
          pv = vL[tid ^ stride]; pi = iL[tid ^ stride];
        } else {
          pv = __shfl_xor(v, stride);
          pi = __shfl_xor(idx, stride);
        }
        const bool sameDir = (up == lower);
        const bool pLess = (pv < v) || (pv == v && pi < idx);
        if (pLess == sameDir) { v = pv; idx = pi; }
      }
    }
    tsv[bh * N_ + tid] = v; tsi[bh * N_ + tid] = idx;
  } else {
    float v = sArr[bh * N_ + tid];
    for (int size = 2; size <= 1024; size <<= 1) {
      for (int stride = size >> 1; stride > 0; stride >>= 1) {
        const bool up = ((tid & size) == 0);
        const bool lower = ((tid & stride) == 0);
        float pv;
        if (stride >= 64) {
          __syncthreads();
          vL[tid] = v;
          __syncthreads();
          pv = vL[tid ^ stride];
        } else {
          pv = __shfl_xor(v, stride);
        }
        const bool sameDir = (up == lower);
        if ((pv < v) == sameDir) v = pv;
      }
    }
    ssv[bh * N_ + tid] = v;
  }
}

// ---- Kernel M: scans, Z/u/v, ranks, qPack scatter, chunk sums, register
//      walk + LDS-float4 emissions -> hp (one block per (b,h)) -------------
__global__ __launch_bounds__(1024, 4) void k_mid3(
    const float* __restrict__ sArr,
    const float* __restrict__ ssv, const float* __restrict__ tsv,
    const int* __restrict__ tsi, const float* __restrict__ Wh,
    float* __restrict__ hp) {
  __shared__ float sL[1024], tvL[1024];
  __shared__ int   tiL[1024];
  __shared__ float cum1L[1024], cum001L[1024];
  __shared__ float uL[1024], vL[1024];
  __shared__ int   cntL[1025], startL[1025];
  __shared__ float4 qPack[1024];        // (i, e^s, e^{0.01s}, pad) per query
  __shared__ float cs1[NCH * 64], cs2[NCH * 64];
  __shared__ float wf1[16], wf2[16];
  __shared__ int   wi1[16];
  const int tid = threadIdx.x, lane = tid & 63, wv = tid >> 6;
  const int bh = blockIdx.x;
  const int b = bh >> 3, hh = bh & 7;
  const int base = bh * N_;

  const float sv = ssv[base + tid];       // sorted s value at rank tid
  const float tj = tsv[base + tid];       // sorted t value at rank tid
  sL[tid] = sv; tvL[tid] = tj; tiL[tid] = tsi[base + tid];
  const float orig_s = sArr[base + tid];
  cntL[tid] = 0;
  if (tid == 0) cntL[1024] = 0;

  // inclusive scans of exp(sorted s), exp(0.01 * sorted s)
  {
    float a1 = __expf(sv), a2 = __expf(0.01f * sv);
#pragma unroll
    for (int off = 1; off < 64; off <<= 1) {
      const float x1 = __shfl_up(a1, off);
      const float x2 = __shfl_up(a2, off);
      if (lane >= off) { a1 += x1; a2 += x2; }
    }
    if (lane == 63) { wf1[wv] = a1; wf2[wv] = a2; }
    __syncthreads();
    float o1 = 0.f, o2 = 0.f;
    for (int ww = 0; ww < 16; ++ww) {
      if (ww < wv) { o1 += wf1[ww]; o2 += wf2[ww]; }
    }
    cum1L[tid] = a1 + o1; cum001L[tid] = a2 + o2;
  }
  __syncthreads();
  const float totalHi = cum1L[1023];

  // per sorted-t rank: Z, u = e^t/Z, v = e^{0.01t}/Z
  {
    const float th = -tj;
    int lo = 0, hi = 1024;   // count of sorted-s <= th
    while (lo < hi) { const int mid = (lo + hi) >> 1; if (sL[mid] <= th) lo = mid + 1; else hi = mid; }
    const float S_lo = (lo > 0) ? cum001L[lo - 1] : 0.f;
    const float S_hi = totalHi - ((lo > 0) ? cum1L[lo - 1] : 0.f);
    const float et = __expf(tj), et001 = __expf(0.01f * tj);
    const float Z = et * S_hi + et001 * S_lo;
    uL[tid] = et / Z; vL[tid] = et001 / Z;
  }

  // query rank for row i=tid: count of t_j <= -s_i ; histogram
  int rk;
  {
    const float th = -orig_s;
    int lo = 0, hi = 1024;
    while (lo < hi) { const int mid = (lo + hi) >> 1; if (tvL[mid] <= th) lo = mid + 1; else hi = mid; }
    rk = lo;
    atomicAdd(&cntL[rk], 1);
  }
  __syncthreads();

  // exclusive scan of cntL -> startL
  {
    const int cown = cntL[tid];
    int a = cown;
#pragma unroll
    for (int off = 1; off < 64; off <<= 1) {
      const int x = __shfl_up(a, off);
      if (lane >= off) a += x;
    }
    if (lane == 63) wi1[wv] = a;
    __syncthreads();
    int o = 0;
    for (int ww = 0; ww < 16; ++ww) {
      if (ww < wv) o += wi1[ww];
    }
    const int incl = a + o;
    startL[tid] = incl - cown;
    if (tid == 1023) startL[1024] = incl;
  }
  __syncthreads();
  cntL[tid] = 0;
  if (tid == 0) cntL[1024] = 0;
  __syncthreads();
  // scatter queries grouped by rank: one float4 record per query
  {
    const int pos = startL[rk] + atomicAdd(&cntL[rk], 1);
    qPack[pos] = make_float4(__int_as_float(tid), __expf(orig_s),
                             __expf(0.01f * orig_s), 0.f);
  }

  // chunk sums of u*Wh, v*Wh; keep this wave's 64 Wh rows in registers
  float wreg[CLN];
  {
    float s1 = 0.f, s2 = 0.f;
#pragma unroll
    for (int k2 = 0; k2 < CLN; ++k2) {
      const int k = wv * CLN + k2;
      const int j = tiL[k];
      const float w = Wh[(base + j) * D_ + lane];
      wreg[k2] = w;
      s1 += uL[k] * w;
      s2 += vL[k] * w;
    }
    cs1[wv * 64 + lane] = s1; cs2[wv * 64 + lane] = s2;
  }
  __syncthreads();   // also orders qPack writes before the emission reads

  // exclusive chunk offsets + total (registers)
  float r1 = 0.f, r2 = 0.f, T1 = 0.f;
  for (int m = 0; m < NCH; ++m) {
    const float v1 = cs1[m * 64 + lane];
    if (m < wv) { r1 += v1; r2 += cs2[m * 64 + lane]; }
    T1 += v1;
  }

  // walk this wave's chunk from registers, emitting queries from qPack
  const int sBase = wv * CLN;
#pragma unroll
  for (int k2 = 0; k2 < CLN; ++k2) {
    const int K = sBase + k2;
    const int qs = startL[K], qe = startL[K + 1];
    for (int q = qs; q < qe; ++q) {
      const float4 qp = qPack[q];
      const int i = __float_as_int(qp.x);
      hp[((b * N_ + i) << 9) + (hh << 6) + lane] =
          qp.y * (T1 - r1) + qp.z * r2;
    }
    r1 += uL[K] * wreg[k2];
    r2 += vL[K] * wreg[k2];
  }
  if (wv == NCH - 1) {
    // queries with rank == 1024 (all t_j <= -s_i): r1 ~= T1, pure lo-branch
    const int qs = startL[1024];
    for (int q = qs; q < N_; ++q) {
      const float4 qp = qPack[q];
      const int i = __float_as_int(qp.x);
      hp[((b * N_ + i) << 9) + (hh << 6) + lane] =
          qp.y * (T1 - r1) + qp.z * r2;
    }
  }
}

// ---- Kernel C: out[row] = hp[row] @ outW + outb (coalesced hp reads) -----
__global__ __launch_bounds__(512) void k_out(
    const float* __restrict__ hp,
    const float* __restrict__ outW, const float* __restrict__ outb,
    float* __restrict__ out) {
  __shared__ float hpL[16 * 512];
  __shared__ float part[8 * 8 * 64];
  const int tid = threadIdx.x;
  const int row0 = blockIdx.x * 16;
  for (int i = tid; i < 16 * 512; i += 512) hpL[i] = hp[row0 * 512 + i];
  __syncthreads();

  const int cc = tid & 63, p = tid >> 6;
  float acc[16];
#pragma unroll
  for (int r = 0; r < 16; ++r) acc[r] = 0.f;
  for (int k = p * 64; k < p * 64 + 64; ++k) {
    const float wvv = outW[k * 64 + cc];
#pragma unroll
    for (int r = 0; r < 16; ++r) acc[r] += hpL[r * 512 + k] * wvv;
  }
  for (int half = 0; half < 2; ++half) {
#pragma unroll
    for (int r = 0; r < 8; ++r) part[(p * 8 + r) * 64 + cc] = acc[half * 8 + r];
    __syncthreads();
    {
      const int r = tid >> 6, c2 = tid & 63;
      float ssum = 0.f;
#pragma unroll
      for (int p2 = 0; p2 < 8; ++p2) ssum += part[(p2 * 8 + r) * 64 + c2];
      out[(row0 + half * 8 + r) * 64 + c2] = outb[c2] + ssum;
    }
    __syncthreads();
  }
}

extern "C" void kernel_launch(void* const* d_in, const int* in_sizes, int n_in,
                              void* d_out, int out_size, void* d_ws, size_t ws_size,
                              hipStream_t stream) {
  const float* h    = (const float*)d_in[0];
  // d_in[1] = adj: all-ones, unused by the module
  const float* W    = (const float*)d_in[2];
  const float* a    = (const float*)d_in[3];
  const float* outW = (const float*)d_in[4];
  const float* outb = (const float*)d_in[5];
  float* out = (float*)d_out;

  float* ws    = (float*)d_ws;
  float* Wh    = ws;                                  // 4,194,304 f (16 MB)
  float* hpG   = Wh + (size_t)BH_ * N_ * D_;          // 4,194,304 f (16 MB)
  float* sArr  = hpG + (size_t)B_ * N_ * 512;         // 65536 f each below
  float* tArr  = sArr + BH_ * N_;
  float* ssv   = tArr + BH_ * N_;
  float* tsv   = ssv + BH_ * N_;
  int*   tsi   = (int*)(tsv + BH_ * N_);
  // total ~33.3 MB of d_ws

  hipLaunchKernelGGL(k_wh,    dim3((B_ * N_) / 16), dim3(256), 0, stream,
                     h, W, a, Wh, sArr, tArr);
  hipLaunchKernelGGL(k_sort1, dim3(BH_ * 2), dim3(1024), 0, stream,
                     sArr, tArr, ssv, tsv, tsi);
  hipLaunchKernelGGL(k_mid3,  dim3(BH_), dim3(1024), 0, stream,
                     sArr, ssv, tsv, tsi, Wh, hpG);
  hipLaunchKernelGGL(k_out,   dim3((B_ * N_) / 16), dim3(512), 0, stream,
                     hpG, outW, outb, out);
}